// Round 6
// baseline (51.481 us; speedup 1.0000x reference)
//
#include <hip/hip_runtime.h>

// SoftHistogram: x[B=64, N=1000, F=256] fp32 -> out[B, F*K=2048] fp32
// R6: MEASUREMENT ROUND. Identical to R5 except phase1 executes 4 redundant
// interleaved copies of the whole read+histogram pass (copy = bid&3; copies of
// the same chunk sit on adjacent bids -> different XCDs). Copies 1-3 write
// unused ws regions; phase2 reads only copy 0, so output is unchanged.
// Purpose: (a) our dispatch becomes top-1 in rocprof -> see FETCH_SIZE /
// hbm_gbps / VALUBusy for the first time; (b) T(R6)-T(R5) = 3 x T_mem(64MB)
// gives the true read-path time free of launch overhead.

constexpr int N = 1000, F = 256, K = 8;
constexpr int CH = 8;              // n-chunks per batch row
constexpr int RC = N / CH;         // 125 rows per chunk
constexpr int WPB = 8;             // waves per block

__global__ __launch_bounds__(512) void softhist_phase1(const float* __restrict__ x,
                                                       float* __restrict__ ws) {
    __shared__ float hist[WPB * K * F];   // 8 waves x [k][f] = 64 KB

    const int bid  = blockIdx.x;          // 0..2047
    const int copy = bid & 3;             // 4 redundant copies
    const int bb   = bid >> 2;            // 0..511 logical block
    const int b  = bb >> 3;
    const int ch = bb & 7;
    const int t  = threadIdx.x;
    const int w  = t >> 6;
    const int l  = t & 63;

#pragma unroll
    for (int z = 0; z < 8; ++z)
        *reinterpret_cast<float4*>(&hist[(z * 512 + t) * 4]) = float4{0.f, 0.f, 0.f, 0.f};
    __syncthreads();

    float* wh = &hist[w * (K * F)];
    const float* base = x + ((size_t)b * N + (size_t)ch * RC) * F + l * 4;

    auto proc = [&](const float4 v) {
        const float xs[4] = {v.x, v.y, v.z, v.w};
#pragma unroll
        for (int i = 0; i < 4; ++i) {
            const float h  = fmaf(xs[i], 8.0f, -0.5f);
            const float kf = __builtin_rintf(h);
            const float kc = __builtin_amdgcn_fmed3f(kf, 0.0f, 7.0f);
            const float y  = fmaf(-2.0f, fabsf(h - kc), 1.0f);
            if (y > 0.0f) {
                const int ki = (int)kc;
                wh[ki * F + 4 * l + i] += y;
            }
        }
    };

    int n = w;
    for (; n + WPB < RC; n += 2 * WPB) {
        const float4 v0 = *reinterpret_cast<const float4*>(base + (size_t)n * F);
        const float4 v1 = *reinterpret_cast<const float4*>(base + (size_t)(n + WPB) * F);
        proc(v0);
        proc(v1);
    }
    if (n < RC)
        proc(*reinterpret_cast<const float4*>(base + (size_t)n * F));
    __syncthreads();

    const int f  = t & 255;
    const int kb = (t >> 8) * 4;
    float4 r;
    float* rr = &r.x;
#pragma unroll
    for (int j = 0; j < 4; ++j) {
        const int off = (kb + j) * F + f;
        float s = 0.0f;
#pragma unroll
        for (int ww = 0; ww < WPB; ++ww) s += hist[ww * (K * F) + off];
        rr[j] = s;
    }
    // copy-0 blocks write the region phase2 reads; copies 1-3 park elsewhere
    *reinterpret_cast<float4*>(ws + ((size_t)(copy * 512 + bb)) * 2048 + f * 8 + kb) = r;
}

__global__ __launch_bounds__(256) void softhist_phase2(const float* __restrict__ ws,
                                                       float* __restrict__ out) {
    const int idx = blockIdx.x * 256 + threadIdx.x;   // 0..131071
    const int b = idx >> 11;
    const int c = idx & 2047;
    float s = 0.0f;
#pragma unroll
    for (int ch = 0; ch < CH; ++ch)
        s += ws[((size_t)(b * CH + ch) << 11) + c];
    out[idx] = s * (1.0f / (float)N);
}

// ---- fallback if ws is unexpectedly small ----
__global__ __launch_bounds__(1024) void softhist_mono(const float* __restrict__ x,
                                                      float* __restrict__ out) {
    constexpr int FG = 32, NSTR = 128;
    __shared__ float part[64 * 264];
    const int bid = blockIdx.x;
    const int b = bid >> 3, f0 = (bid & 7) * FG;
    const int t = threadIdx.x;
    const int fl8 = t & 7, nsub = t >> 3;
    const int w = t >> 6, l = t & 63;

    float acc[4][K];
#pragma unroll
    for (int i = 0; i < 4; ++i)
#pragma unroll
        for (int k = 0; k < K; ++k) acc[i][k] = 0.0f;

    const float* base = x + (size_t)b * N * F + f0 + fl8 * 4;
#define PROC4(v)                                                             \
    {                                                                        \
        const float xs[4] = {(v).x, (v).y, (v).z, (v).w};                    \
        _Pragma("unroll")                                                    \
        for (int i = 0; i < 4; ++i) {                                        \
            const float p = fmaf(xs[i], 16.0f, -1.0f);                       \
            float aprev = -1.0f - p;                                         \
            _Pragma("unroll")                                                \
            for (int k = 0; k < K; ++k) {                                    \
                const float a = (float)(2 * k + 1) - p;                      \
                acc[i][k] += __builtin_amdgcn_fmed3f(0.0f, a, -aprev);       \
                aprev = a;                                                   \
            }                                                                \
        }                                                                    \
    }
    int n = nsub;
    for (; n + NSTR < N; n += 2 * NSTR) {
        const float4 v0 = *reinterpret_cast<const float4*>(base + (size_t)n * F);
        const float4 v1 = *reinterpret_cast<const float4*>(base + (size_t)(n + NSTR) * F);
        PROC4(v0);
        PROC4(v1);
    }
    if (n < N) {
        const float4 v = *reinterpret_cast<const float4*>(base + (size_t)n * F);
        PROC4(v);
    }
#undef PROC4
#pragma unroll
    for (int i = 0; i < 4; ++i)
#pragma unroll
        for (int k = 0; k < K; ++k) acc[i][k] += __shfl_xor(acc[i][k], 32, 64);
    if (l < 32) {
        const int g = w * 4 + (l >> 3);
        float* dst = &part[g * 264 + fl8 * 33];
#pragma unroll
        for (int i = 0; i < 4; ++i)
#pragma unroll
            for (int k = 0; k < K; ++k) dst[i * 8 + k] = acc[i][k];
    }
    __syncthreads();
    if (t < FG * K) {
        const int off = (t >> 5) * 33 + (t & 31);
        float s = 0.0f;
#pragma unroll
        for (int g = 0; g < 64; ++g) s += part[g * 264 + off];
        out[(size_t)b * (F * K) + f0 * K + t] = s * (1.0f / (float)N);
    }
}

extern "C" void kernel_launch(void* const* d_in, const int* in_sizes, int n_in,
                              void* d_out, int out_size, void* d_ws, size_t ws_size,
                              hipStream_t stream) {
    const float* x = (const float*)d_in[0];
    float* out = (float*)d_out;
    const size_t ws_needed = (size_t)2048 * 2048 * sizeof(float);  // 16 MB
    if (ws_size >= ws_needed) {
        float* ws = (float*)d_ws;
        softhist_phase1<<<dim3(2048), dim3(512), 0, stream>>>(x, ws);
        softhist_phase2<<<dim3(512), dim3(256), 0, stream>>>(ws, out);
    } else {
        softhist_mono<<<dim3(512), dim3(1024), 0, stream>>>(x, out);
    }
}

// Round 7
// 20.282 us; speedup vs baseline: 2.5383x; 2.5383x over previous
//
#include <hip/hip_runtime.h>

// SoftHistogram: x[B=64, N=1000, F=256] fp32 -> out[B, F*K=2048] fp32
// out[b, f*8+k] = mean_n relu(1 - 16*|x[b,n,f] - (k+0.5)/8|)
//
// R7 = R5 + bank-conflict fix (R6's counters showed 7.07M conflict cycles).
// Nearest-bin: u = 8x-0.5, k* = clamp(round(u),0,7), y = relu(1-2|u-k*|);
// at most one nonzero bin per element. Wave-private LDS histograms.
// KEY FIX: hist slot for feature f=4l+i is ki*256 + i*64 + l (perm(f) =
// (f&3)*64 + f>>2), so the RMW bank = l%32 -> conflict-free (2 lanes/bank
// is free) for every (i, ki). R5's ki*256+4l+i hit only 8 banks (8-way).
// Block reduce un-permutes into ws (4-way on 32 reads/thread, negligible).

constexpr int N = 1000, F = 256, K = 8;
constexpr int CH = 8;              // n-chunks per batch row
constexpr int RC = N / CH;         // 125 rows per chunk
constexpr int WPB = 8;             // waves per block

__global__ __launch_bounds__(512) void softhist_phase1(const float* __restrict__ x,
                                                       float* __restrict__ ws) {
    __shared__ float hist[WPB * K * F];   // 8 waves x [k][slot] = 64 KB

    const int bid = blockIdx.x;
    const int b  = bid >> 3;
    const int ch = bid & 7;
    const int t  = threadIdx.x;
    const int w  = t >> 6;             // wave 0..7
    const int l  = t & 63;             // lane

    // zero the histograms
#pragma unroll
    for (int z = 0; z < 8; ++z)
        *reinterpret_cast<float4*>(&hist[(z * 512 + t) * 4]) = float4{0.f, 0.f, 0.f, 0.f};
    __syncthreads();

    float* wh = &hist[w * (K * F)];
    const float* base = x + ((size_t)b * N + (size_t)ch * RC) * F + l * 4;

    auto proc = [&](const float4 v) {
        const float xs[4] = {v.x, v.y, v.z, v.w};
#pragma unroll
        for (int i = 0; i < 4; ++i) {
            const float h  = fmaf(xs[i], 8.0f, -0.5f);          // u = 8x - 0.5
            const float kf = __builtin_rintf(h);                 // v_rndne
            const float kc = __builtin_amdgcn_fmed3f(kf, 0.0f, 7.0f);
            const float y  = fmaf(-2.0f, fabsf(h - kc), 1.0f);   // 1 - 2|u-k*|
            if (y > 0.0f) {                                      // ~34% of lanes
                const int ki = (int)kc;
                wh[ki * F + (i << 6) + l] += y;  // bank = l%32: conflict-free
            }
        }
    };

    int n = w;
    for (; n + WPB < RC; n += 2 * WPB) {
        const float4 v0 = *reinterpret_cast<const float4*>(base + (size_t)n * F);
        const float4 v1 = *reinterpret_cast<const float4*>(base + (size_t)(n + WPB) * F);
        proc(v0);
        proc(v1);
    }
    if (n < RC)
        proc(*reinterpret_cast<const float4*>(base + (size_t)n * F));
    __syncthreads();

    // Reduce 8 wave-hists -> 2048 block partials in output order c = f*8+k.
    // Thread t: f = t&255, k = 4*(t>>8)+j; slot = k*256 + perm(f).
    const int f  = t & 255;
    const int kb = (t >> 8) * 4;
    const int pf = ((f & 3) << 6) + (f >> 2);   // perm(f)
    float4 r;
    float* rr = &r.x;
#pragma unroll
    for (int j = 0; j < 4; ++j) {
        const int off = (kb + j) * F + pf;
        float s = 0.0f;
#pragma unroll
        for (int ww = 0; ww < WPB; ++ww) s += hist[ww * (K * F) + off];
        rr[j] = s;
    }
    *reinterpret_cast<float4*>(ws + (size_t)bid * 2048 + f * 8 + kb) = r;
}

__global__ __launch_bounds__(256) void softhist_phase2(const float* __restrict__ ws,
                                                       float* __restrict__ out) {
    const int idx = blockIdx.x * 256 + threadIdx.x;   // 0..131071
    const int b = idx >> 11;
    const int c = idx & 2047;
    float s = 0.0f;
#pragma unroll
    for (int ch = 0; ch < CH; ++ch)
        s += ws[((size_t)(b * CH + ch) << 11) + c];
    out[idx] = s * (1.0f / (float)N);
}

// ---- fallback if ws is unexpectedly small ----
__global__ __launch_bounds__(1024) void softhist_mono(const float* __restrict__ x,
                                                      float* __restrict__ out) {
    constexpr int FG = 32, NSTR = 128;
    __shared__ float part[64 * 264];
    const int bid = blockIdx.x;
    const int b = bid >> 3, f0 = (bid & 7) * FG;
    const int t = threadIdx.x;
    const int fl8 = t & 7, nsub = t >> 3;
    const int w = t >> 6, l = t & 63;

    float acc[4][K];
#pragma unroll
    for (int i = 0; i < 4; ++i)
#pragma unroll
        for (int k = 0; k < K; ++k) acc[i][k] = 0.0f;

    const float* base = x + (size_t)b * N * F + f0 + fl8 * 4;
#define PROC4(v)                                                             \
    {                                                                        \
        const float xs[4] = {(v).x, (v).y, (v).z, (v).w};                    \
        _Pragma("unroll")                                                    \
        for (int i = 0; i < 4; ++i) {                                        \
            const float p = fmaf(xs[i], 16.0f, -1.0f);                       \
            float aprev = -1.0f - p;                                         \
            _Pragma("unroll")                                                \
            for (int k = 0; k < K; ++k) {                                    \
                const float a = (float)(2 * k + 1) - p;                      \
                acc[i][k] += __builtin_amdgcn_fmed3f(0.0f, a, -aprev);       \
                aprev = a;                                                   \
            }                                                                \
        }                                                                    \
    }
    int n = nsub;
    for (; n + NSTR < N; n += 2 * NSTR) {
        const float4 v0 = *reinterpret_cast<const float4*>(base + (size_t)n * F);
        const float4 v1 = *reinterpret_cast<const float4*>(base + (size_t)(n + NSTR) * F);
        PROC4(v0);
        PROC4(v1);
    }
    if (n < N) {
        const float4 v = *reinterpret_cast<const float4*>(base + (size_t)n * F);
        PROC4(v);
    }
#undef PROC4
#pragma unroll
    for (int i = 0; i < 4; ++i)
#pragma unroll
        for (int k = 0; k < K; ++k) acc[i][k] += __shfl_xor(acc[i][k], 32, 64);
    if (l < 32) {
        const int g = w * 4 + (l >> 3);
        float* dst = &part[g * 264 + fl8 * 33];
#pragma unroll
        for (int i = 0; i < 4; ++i)
#pragma unroll
            for (int k = 0; k < K; ++k) dst[i * 8 + k] = acc[i][k];
    }
    __syncthreads();
    if (t < FG * K) {
        const int off = (t >> 5) * 33 + (t & 31);
        float s = 0.0f;
#pragma unroll
        for (int g = 0; g < 64; ++g) s += part[g * 264 + off];
        out[(size_t)b * (F * K) + f0 * K + t] = s * (1.0f / (float)N);
    }
}

extern "C" void kernel_launch(void* const* d_in, const int* in_sizes, int n_in,
                              void* d_out, int out_size, void* d_ws, size_t ws_size,
                              hipStream_t stream) {
    const float* x = (const float*)d_in[0];
    float* out = (float*)d_out;
    const size_t ws_needed = (size_t)512 * 2048 * sizeof(float);  // 4 MB
    if (ws_size >= ws_needed) {
        float* ws = (float*)d_ws;
        softhist_phase1<<<dim3(512), dim3(512), 0, stream>>>(x, ws);
        softhist_phase2<<<dim3(512), dim3(256), 0, stream>>>(ws, out);
    } else {
        softhist_mono<<<dim3(512), dim3(1024), 0, stream>>>(x, out);
    }
}